// Round 3
// baseline (326.767 us; speedup 1.0000x reference)
//
#include <hip/hip_runtime.h>

#define NUM_BINS 128
#define BATCH 128
#define HW (512 * 512)            // elements per image
#define GRID 1024                 // co-resident: 4 blocks/CU on 256 CUs
#define TPB 256
#define BPI (GRID / BATCH)        // 8 blocks per image
#define CHUNK (HW / BPI)          // 32768 elements per block
#define NWAVES (TPB / 64)
#define MAGIC 0x5A5A1234u

typedef float f4 __attribute__((ext_vector_type(4)));

// ---------------------------------------------------------------------------
// Single fused kernel (cooperative launch => all 1024 blocks co-resident, so
// per-image flag spin is deadlock-free regardless of dispatch order).
// Phase 1: per-block partial histogram (torch.histc(0,1) semantics) -> publish
//          via agent-scope stores + release flag.
// Phase 2: spin on own image's 8 flags, reduce partials, tiny MLP (redundant
//          per block, sub-µs), scale own chunk with nontemporal stores so the
//          write stream doesn't evict x from L3.
// ---------------------------------------------------------------------------
__global__ __launch_bounds__(TPB, 4) void fused_kernel(
    const float* __restrict__ x,
    unsigned int* __restrict__ part,    // [GRID][NUM_BINS]
    unsigned int* __restrict__ flags,   // [GRID], zeroed by memset
    const float* __restrict__ W1, const float* __restrict__ b1,
    const float* __restrict__ W2, const float* __restrict__ b2,
    float* __restrict__ out) {
    __shared__ unsigned int lh[NWAVES][NUM_BINS];
    __shared__ float hist_s[NUM_BINS];
    __shared__ float w_s;

    const int tid = threadIdx.x;
    const int wv  = tid >> 6;
    const int b   = blockIdx.x >> 3;    // / BPI
    const int blk = blockIdx.x & (BPI - 1);

    for (int i = tid; i < NWAVES * NUM_BINS; i += TPB)
        ((unsigned int*)lh)[i] = 0u;
    __syncthreads();

    // ---- Phase 1: histogram own chunk -----------------------------------
    const f4* xp = (const f4*)(x + (size_t)b * HW) + (size_t)blk * (CHUNK / 4);
    const int n4 = CHUNK / 4;           // 8192 -> 32 f4 per thread
#pragma unroll 4
    for (int i = tid; i < n4; i += TPB) {
        f4 v = xp[i];
#pragma unroll
        for (int k = 0; k < 4; ++k) {
            float f = v[k];
            // trunc == floor for f>=0; f==1.0 -> bin 127 via min
            int idx = min((int)(f * (float)NUM_BINS), NUM_BINS - 1);
            if (f >= 0.0f && f <= 1.0f) atomicAdd(&lh[wv][idx], 1u);
        }
    }
    __syncthreads();

    // publish this block's partial with device-coherent stores
    if (tid < NUM_BINS) {
        unsigned int s = lh[0][tid] + lh[1][tid] + lh[2][tid] + lh[3][tid];
        __hip_atomic_store(&part[(size_t)blockIdx.x * NUM_BINS + tid], s,
                           __ATOMIC_RELAXED, __HIP_MEMORY_SCOPE_AGENT);
    }
    __syncthreads();
    if (tid == 0)
        __hip_atomic_store(&flags[blockIdx.x], MAGIC,
                           __ATOMIC_RELEASE, __HIP_MEMORY_SCOPE_AGENT);

    // ---- Phase 2: wait for image b's 8 partials --------------------------
    if (tid < BPI) {
        const unsigned int* fp = &flags[b * BPI + tid];
        while (__hip_atomic_load(fp, __ATOMIC_ACQUIRE,
                                 __HIP_MEMORY_SCOPE_AGENT) != MAGIC)
            __builtin_amdgcn_s_sleep(2);
    }
    __syncthreads();

    if (tid < NUM_BINS) {
        unsigned int s = 0u;
#pragma unroll
        for (int j = 0; j < BPI; ++j)
            s += __hip_atomic_load(&part[(size_t)(b * BPI + j) * NUM_BINS + tid],
                                   __ATOMIC_RELAXED, __HIP_MEMORY_SCOPE_AGENT);
        hist_s[tid] = (float)s;         // exact: counts <= 262144 < 2^24
    }
    __syncthreads();

    // tiny MLP, lanes 0..15 of wave 0 (one hidden unit each)
    if (tid < 16) {
        float acc = b1[tid];
#pragma unroll 8
        for (int k = 0; k < NUM_BINS; ++k)
            acc = fmaf(hist_s[k], W1[k * 16 + tid], acc);
        float h = fmaxf(acc, 0.0f) * W2[tid];
#pragma unroll
        for (int off = 8; off > 0; off >>= 1) h += __shfl_down(h, off);
        if (tid == 0) w_s = h + b2[0];
    }
    __syncthreads();

    // ---- Phase 3: scale own chunk ---------------------------------------
    const float s = w_s;
    f4* op = (f4*)(out + (size_t)b * HW) + (size_t)blk * (CHUNK / 4);
#pragma unroll 4
    for (int i = tid; i < n4; i += TPB) {
        f4 v = xp[i];
        __builtin_nontemporal_store(v * s, &op[i]);
    }
}

extern "C" void kernel_launch(void* const* d_in, const int* in_sizes, int n_in,
                              void* d_out, int out_size, void* d_ws, size_t ws_size,
                              hipStream_t stream) {
    const float* x  = (const float*)d_in[0];
    const float* W1 = (const float*)d_in[1];
    const float* b1 = (const float*)d_in[2];
    const float* W2 = (const float*)d_in[3];
    const float* b2 = (const float*)d_in[4];
    float* out = (float*)d_out;

    unsigned int* flags = (unsigned int*)d_ws;                 // 4 KiB
    unsigned int* part  = flags + GRID;                        // 512 KiB

    hipMemsetAsync(flags, 0, GRID * sizeof(unsigned int), stream);

    void* args[] = {(void*)&x, (void*)&part, (void*)&flags,
                    (void*)&W1, (void*)&b1, (void*)&W2, (void*)&b2,
                    (void*)&out};
    hipLaunchCooperativeKernel((void*)fused_kernel, dim3(GRID), dim3(TPB),
                               args, 0, stream);
}